// Round 5
// baseline (291.294 us; speedup 1.0000x reference)
//
#include <hip/hip_runtime.h>

// Problem constants
#define BB   16
#define CC   16
#define HH   256
#define WW   256
#define HID  128
#define OUTC 13

typedef short short8 __attribute__((ext_vector_type(8)));
typedef float floatx16 __attribute__((ext_vector_type(16)));
typedef float floatx4 __attribute__((ext_vector_type(4)));

// ---- helpers ----
__device__ __forceinline__ unsigned short f2bf(float x) {
    unsigned int u = __float_as_uint(x);
    u += 0x7fffu + ((u >> 16) & 1u);          // round-to-nearest-even
    return (unsigned short)(u >> 16);
}

// packed f32x2 -> bf16x2 (RNE), 1 instr
__device__ __forceinline__ unsigned int cvt_pk_bf16(float lo, float hi) {
    unsigned int d;
    asm("v_cvt_pk_bf16_f32 %0, %1, %2" : "=v"(d) : "v"(lo), "v"(hi));
    return d;
}

// ws layout: W1F frags [mtG 0..3][tap 0..8][lane 0..63][8 bf16]  = 36864 B
//            W2F frags [s 0..7][lane 0..63][8 bf16]              =  8192 B at +36864
#define W1F_BYTES 36864
#define W2F_OFF   36864

// ================= prep kernel: bake bf16 weight fragments ==================
__global__ __launch_bounds__(256) void gca_prep(
    const float* __restrict__ w1, const float* __restrict__ w2,
    unsigned char* __restrict__ ws)
{
    const int id = blockIdx.x * 256 + threadIdx.x;   // 2816 total
    const float SX[9] = {-1.f, 0.f, 1.f, -2.f, 0.f, 2.f, -1.f, 0.f, 1.f};
    const float SY[9] = {-1.f, -2.f, -1.f, 0.f, 0.f, 0.f, 1.f, 2.f, 1.f};

    if (id < 2304) {                                  // W1eff frags
        const int mtG  = id / 576;
        const int rem  = id % 576;
        const int tap  = rem / 64;
        const int lane = rem % 64;
        const int p  = lane & 31, hi = lane >> 5;
        const int hid = 32 * mtG + p;
        const float cen = (tap == 4) ? 1.f : 0.f;
        const float sxv = SX[tap], syv = SY[tap];
        const float* wr = w1 + hid * 48;
        unsigned int o[4];
        for (int k = 0; k < 4; ++k) {
            int c0 = 8 * hi + 2 * k;
            float v0 = wr[c0]     * cen + wr[16 + c0]     * sxv + wr[32 + c0]     * syv;
            float v1 = wr[c0 + 1] * cen + wr[16 + c0 + 1] * sxv + wr[32 + c0 + 1] * syv;
            o[k] = (unsigned int)f2bf(v0) | ((unsigned int)f2bf(v1) << 16);
        }
        *(uint4*)(ws + (size_t)id * 16) = make_uint4(o[0], o[1], o[2], o[3]);
    } else if (id < 2816) {                           // W2 (padded outc 13->32) frags
        const int id2 = id - 2304;
        const int s    = id2 / 64;
        const int lane = id2 % 64;
        const int outc = lane & 31, hi = lane >> 5;
        unsigned int o[4];
        for (int k = 0; k < 4; ++k) {
            int hid0 = 16 * s + 8 * hi + 2 * k;
            float v0 = (outc < OUTC) ? w2[outc * HID + hid0]     : 0.f;
            float v1 = (outc < OUTC) ? w2[outc * HID + hid0 + 1] : 0.f;
            o[k] = (unsigned int)f2bf(v0) | ((unsigned int)f2bf(v1) << 16);
        }
        *(uint4*)(ws + W2F_OFF + (size_t)id2 * 16) = make_uint4(o[0], o[1], o[2], o[3]);
    }
}

// ================= main kernel ==============================================
// Block = 256 thr = 4 INDEPENDENT waves. Each wave computes FULL rows
// (all 128 hidden units) by itself: 4 iterations x 1 row/wave = 16 rows.
// NO barriers in the t-loop (only after staging) -> waves are free-running
// instruction streams; per-block critical path no longer couples waves.
// LDS: bf16 input tile only, [18 rows][34 cols][16 c], 40B px stride = 24.5 KB.
// NOTES (measured, rounds 2-4):
//  - NO __launch_bounds__ occupancy clause: (256,4) capped unified VGPR+AGPR
//    at ~128 -> scratch spills -> FETCH 120->670 MB, WRITE 64->205 MB, 2x slow.
//  - pair-split (2 waves/row + LDS exchange + 1-2 barriers/iter): 137-165 µs,
//    latency-bound at ~2 blocks/CU; lockstep propagates every wave's stalls.
//  - WRITE_SIZE == 65536 KB exact is the no-spill tripwire.
#define TILE_DW 6120

__global__ __launch_bounds__(256) void gca_main(
    const float* __restrict__ in,
    const float* __restrict__ b1,
    const unsigned char* __restrict__ ws,
    float* __restrict__ out)
{
    __shared__ unsigned int lds[TILE_DW];

    const int tid  = threadIdx.x;
    const int wid  = tid >> 6;
    const int lane = tid & 63;
    const int p    = lane & 31;    // pixel-in-group / m-index
    const int hi   = lane >> 5;    // k-half selector

    const int bI = blockIdx.x >> 7;          // image
    const int rm = blockIdx.x & 127;
    const int y0 = (rm >> 3) << 4;           // 16-row span
    const int x0 = (rm & 7)  << 5;           // 32-px span

    const float* inb  = in  + ((size_t)bI << 20);
    float*       outb = out + ((size_t)bI << 20);

    // ---- prologue: passthrough channels 0..2 as 16B copy (plain stores) ----
    {
        int e = tid;
#pragma unroll
        for (int it = 0; it < 2; ++it) {
            if (e < 384) {
                int c = e >> 7, rem = e & 127, rw = rem >> 3, q = rem & 7;
                int idx = (c << 16) + ((y0 + rw) << 8) + x0 + (q << 2);
                *(floatx4*)(outb + idx) = *(const floatx4*)(inb + idx);
            }
            e += 256;
        }
    }

    // ---- stage halo tile (rows y0-1..y0+16, cols x0-1..x0+32), f32 -> bf16 ----
    // group g = channel pair (2g, 2g+1); lane l = column. No div/mod, packed cvt.
    {
        const int g = tid >> 5, l = tid & 31;
        const float* cp = inb + ((size_t)(2 * g) << 16);
        const int xA = (x0 + l - 1) & 255;
        const int xB = (x0 + l + 31) & 255;      // cols 32,33 (l<2 only)
        const int ldsA = l * 10 + g;
        const int ldsB = (l + 32) * 10 + g;
        const bool doB = (l < 2);
        for (int rw = 0; rw < 18; ++rw) {
            const int yo = ((y0 + rw - 1) & 255) << 8;
            float a0 = cp[yo + xA], a1 = cp[yo + xA + 65536];
            lds[rw * 340 + ldsA] = cvt_pk_bf16(a0, a1);
            if (doB) {
                float c0 = cp[yo + xB], c1 = cp[yo + xB + 65536];
                lds[rw * 340 + ldsB] = cvt_pk_bf16(c0, c1);
            }
        }
    }
    __syncthreads();            // the ONLY block-wide barrier

    const unsigned char* w1f = ws;                 // all 4 mtG used by every wave
    const unsigned char* w2f = ws + W2F_OFF;       // all 8 k-slices used

    // epilogue constants: acc2 reg r -> output channel; off/validity
    int off16[16]; bool val16[16];
#pragma unroll
    for (int r = 0; r < 16; ++r) {
        int oc = (r & 3) + 8 * (r >> 2) + 4 * hi;
        val16[r] = (oc < OUTC);
        off16[r] = (3 + oc) << 16;
    }

#pragma unroll 1
    for (int t = 0; t < 4; ++t) {
        const int rr4   = 4 * t + wid;            // row-in-tile (0..15)
        const int row   = y0 + rr4;               // image row of this wave
        const int ibase = (row << 8) + x0 + p;

        // ---- residual preload (all valid channels) — hides under GEMM1 ----
        float rs[16];
#pragma unroll
        for (int r = 0; r < 16; ++r)
            rs[r] = val16[r] ? inb[ibase + off16[r]] : 0.f;

        // ---- acc1 init = b1 (pre-relu bias), 4 m-tiles = all 128 hids ----
        floatx16 acc1[4];
#pragma unroll
        for (int m = 0; m < 4; ++m) {
            const int hb = 32 * m + 4 * hi;
#pragma unroll
            for (int rr = 0; rr < 4; ++rr) {
                float4 bv = *(const float4*)(b1 + hb + 8 * rr);
                acc1[m][4 * rr + 0] = bv.x;
                acc1[m][4 * rr + 1] = bv.y;
                acc1[m][4 * rr + 2] = bv.z;
                acc1[m][4 * rr + 3] = bv.w;
            }
        }

        // ---- GEMM1: 9 taps (K=16 each), A = W1eff frags, B = bf16 pixel tile ----
#pragma unroll
        for (int tap = 0; tap < 9; ++tap) {
            const int tr  = rr4 + tap / 3;            // tile row (dy+1 folded in)
            const int col = p + tap % 3;              // tile col (dx+1 folded in)
            const int dwo = (tr * 34 + col) * 10 + 4 * hi;
            union { unsigned int u[4]; short8 s; } bfr;
            uint2 lo2 = *(const uint2*)&lds[dwo];
            uint2 hi2 = *(const uint2*)&lds[dwo + 2];
            bfr.u[0] = lo2.x; bfr.u[1] = lo2.y; bfr.u[2] = hi2.x; bfr.u[3] = hi2.y;
#pragma unroll
            for (int m = 0; m < 4; ++m) {
                short8 af = *(const short8*)(w1f + (size_t)((m * 9 + tap) * 64 + lane) * 16);
                acc1[m] = __builtin_amdgcn_mfma_f32_32x32x16_bf16(af, bfr.s, acc1[m], 0, 0, 0);
            }
        }

        // ---- relu + pack h[128] (packed cvt) ----
        uint2 hrun[16];
#pragma unroll
        for (int m = 0; m < 4; ++m)
#pragma unroll
            for (int rr = 0; rr < 4; ++rr) {
                float h0 = fmaxf(acc1[m][4 * rr + 0], 0.f);
                float h1 = fmaxf(acc1[m][4 * rr + 1], 0.f);
                float h2 = fmaxf(acc1[m][4 * rr + 2], 0.f);
                float h3 = fmaxf(acc1[m][4 * rr + 3], 0.f);
                hrun[4 * m + rr].x = cvt_pk_bf16(h0, h1);
                hrun[4 * m + rr].y = cvt_pk_bf16(h2, h3);
            }

        // ---- acc2 C-init = residual ----
        floatx16 acc2;
#pragma unroll
        for (int r = 0; r < 16; ++r) acc2[r] = rs[r];

        // ---- GEMM2 over K=128 (8 slices): D[outc32][pixel32] ----
#pragma unroll
        for (int sp = 0; sp < 8; ++sp) {
            uint2 r0 = hrun[2 * sp];
            uint2 r1 = hrun[2 * sp + 1];
            uint2 x0s, x1s;
            x0s.x = (unsigned int)__shfl_xor((int)r0.x, 32);
            x0s.y = (unsigned int)__shfl_xor((int)r0.y, 32);
            x1s.x = (unsigned int)__shfl_xor((int)r1.x, 32);
            x1s.y = (unsigned int)__shfl_xor((int)r1.y, 32);
            union { unsigned int u[4]; short8 s; } b2;
            uint2 lo = hi ? x1s : r0;
            uint2 hg = hi ? r1  : x0s;
            b2.u[0] = lo.x; b2.u[1] = lo.y; b2.u[2] = hg.x; b2.u[3] = hg.y;
            short8 a2 = *(const short8*)(w2f + (size_t)(sp * 64 + lane) * 16);
            acc2 = __builtin_amdgcn_mfma_f32_32x32x16_bf16(a2, b2.s, acc2, 0, 0, 0);
        }

        // ---- store own row's 13 channels (no exchange needed) ----
#pragma unroll
        for (int r = 0; r < 16; ++r)
            if (val16[r])
                outb[ibase + off16[r]] = acc2[r];
    }
}

extern "C" void kernel_launch(void* const* d_in, const int* in_sizes, int n_in,
                              void* d_out, int out_size, void* d_ws, size_t ws_size,
                              hipStream_t stream) {
    const float* x  = (const float*)d_in[0];
    const float* w1 = (const float*)d_in[1];
    const float* b1 = (const float*)d_in[2];
    const float* w2 = (const float*)d_in[3];
    float* out = (float*)d_out;
    unsigned char* ws = (unsigned char*)d_ws;

    hipLaunchKernelGGL(gca_prep, dim3(11), dim3(256), 0, stream, w1, w2, ws);
    hipLaunchKernelGGL(gca_main, dim3(2048), dim3(256), 0, stream, x, b1, ws, out);
}

// Round 6
// 248.890 us; speedup vs baseline: 1.1704x; 1.1704x over previous
//
#include <hip/hip_runtime.h>

// Problem constants
#define BB   16
#define CC   16
#define HH   256
#define WW   256
#define HID  128
#define OUTC 13

typedef short short8 __attribute__((ext_vector_type(8)));
typedef float floatx16 __attribute__((ext_vector_type(16)));

// ---- helpers ----
__device__ __forceinline__ unsigned short f2bf(float x) {
    unsigned int u = __float_as_uint(x);
    u += 0x7fffu + ((u >> 16) & 1u);          // round-to-nearest-even
    return (unsigned short)(u >> 16);
}
__device__ __forceinline__ unsigned int pack2(float lo, float hi) {
    return (unsigned int)f2bf(lo) | ((unsigned int)f2bf(hi) << 16);
}

// ws layout: W1F frags [mtG 0..3][tap 0..8][lane 0..63][8 bf16]  = 36864 B
//            W2F frags [s 0..7][lane 0..63][8 bf16]              =  8192 B at +36864
#define W1F_BYTES 36864
#define W2F_OFF   36864

// ================= prep kernel: bake bf16 weight fragments ==================
__global__ __launch_bounds__(256) void gca_prep(
    const float* __restrict__ w1, const float* __restrict__ w2,
    unsigned char* __restrict__ ws)
{
    const int id = blockIdx.x * 256 + threadIdx.x;   // 2816 total
    const float SX[9] = {-1.f, 0.f, 1.f, -2.f, 0.f, 2.f, -1.f, 0.f, 1.f};
    const float SY[9] = {-1.f, -2.f, -1.f, 0.f, 0.f, 0.f, 1.f, 2.f, 1.f};

    if (id < 2304) {                                  // W1eff frags
        const int mtG  = id / 576;
        const int rem  = id % 576;
        const int tap  = rem / 64;
        const int lane = rem % 64;
        const int p  = lane & 31, hi = lane >> 5;
        const int hid = 32 * mtG + p;
        const float cen = (tap == 4) ? 1.f : 0.f;
        const float sxv = SX[tap], syv = SY[tap];
        const float* wr = w1 + hid * 48;
        unsigned int o[4];
        for (int k = 0; k < 4; ++k) {
            int c0 = 8 * hi + 2 * k;
            float v0 = wr[c0]     * cen + wr[16 + c0]     * sxv + wr[32 + c0]     * syv;
            float v1 = wr[c0 + 1] * cen + wr[16 + c0 + 1] * sxv + wr[32 + c0 + 1] * syv;
            o[k] = (unsigned int)f2bf(v0) | ((unsigned int)f2bf(v1) << 16);
        }
        *(uint4*)(ws + (size_t)id * 16) = make_uint4(o[0], o[1], o[2], o[3]);
    } else if (id < 2816) {                           // W2 (padded outc 13->32) frags
        const int id2 = id - 2304;
        const int s    = id2 / 64;
        const int lane = id2 % 64;
        const int outc = lane & 31, hi = lane >> 5;
        unsigned int o[4];
        for (int k = 0; k < 4; ++k) {
            int hid0 = 16 * s + 8 * hi + 2 * k;
            float v0 = (outc < OUTC) ? w2[outc * HID + hid0]     : 0.f;
            float v1 = (outc < OUTC) ? w2[outc * HID + hid0 + 1] : 0.f;
            o[k] = (unsigned int)f2bf(v0) | ((unsigned int)f2bf(v1) << 16);
        }
        *(uint4*)(ws + W2F_OFF + (size_t)id2 * 16) = make_uint4(o[0], o[1], o[2], o[3]);
    }
}

// ================= main kernel ==============================================
// Block = 128 thr = 2 waves = ONE pair; 8-row x 32-px span; 4096 blocks.
// Same proven instruction stream as the 137-µs baseline (2 barriers/iter,
// epilogue residual+store on wave0, passthrough on wave1, per-iter W2 loads),
// but half-size blocks double the resident-wave ceiling:
// LDS 18.2 KB -> 8 blocks/CU (vs 4); VGPR ~100 -> 5 waves/SIMD; 16 waves/CU.
// MEASURED HISTORY (rounds 2-5):
//  - (256,4) launch bound -> unified-RF spills -> FETCH x5, WRITE x3, 2x slow.
//  - full-row-per-wave (192 VGPR, 0 barriers): occ 11.6%, 210 µs. Latency-
//    bound regime: wave count beats per-wave instruction efficiency.
//  - WRITE_SIZE == 65536 KB exact is the no-spill tripwire.
#define TILE_DW 3400                      // 10 rows x 34 cols x 10 dw/px
#define CBUF_DW 1152                      // 64 lanes x 18 dw
#define LDS_DW  (TILE_DW + CBUF_DW)       // 4552 dw = 18208 B

__global__ __launch_bounds__(128) void gca_main(
    const float* __restrict__ in,
    const float* __restrict__ b1,
    const unsigned char* __restrict__ ws,
    float* __restrict__ out)
{
    __shared__ unsigned int lds[LDS_DW];

    const int tid  = threadIdx.x;
    const int wid  = tid >> 6;
    const int lane = tid & 63;
    const int hw   = wid;          // hid-half (0 or 1)
    const int p    = lane & 31;    // pixel-in-group / m-index
    const int hi   = lane >> 5;    // k-half selector

    const int bI = blockIdx.x >> 8;          // image
    const int rm = blockIdx.x & 255;
    const int y0 = (rm >> 3) << 3;           // 8-row span
    const int x0 = (rm & 7)  << 5;           // 32-px span

    const float* inb  = in  + ((size_t)bI << 20);
    float*       outb = out + ((size_t)bI << 20);

    // ---- stage halo tile (rows y0-1..y0+8, cols x0-1..x0+32), f32 -> bf16 ----
    // g = tid>>5 in [0,4): this thread stages channel-pairs g and g+4;
    // l = tid&31 = column. No div/mod; f2bf (RNE) packing.
    {
        const int g = tid >> 5, l = tid & 31;
        const float* cp0 = inb + ((size_t)(2 * g) << 16);      // channels 2g, 2g+1
        const int xA = (x0 + l - 1) & 255;
        const int xB = (x0 + l + 31) & 255;                    // cols 32,33 (l<2)
        const int ldsA = l * 10 + g;
        const int ldsB = (l + 32) * 10 + g;
        const bool doB = (l < 2);
        for (int rw = 0; rw < 10; ++rw) {
            const int yo = ((y0 + rw - 1) & 255) << 8;
            float a0 = cp0[yo + xA];
            float a1 = cp0[yo + xA + (1 << 16)];
            float b0 = cp0[yo + xA + (8 << 16)];               // channels 2g+8, 2g+9
            float b1v = cp0[yo + xA + (9 << 16)];
            lds[rw * 340 + ldsA]     = pack2(a0, a1);
            lds[rw * 340 + ldsA + 4] = pack2(b0, b1v);
            if (doB) {
                float c0 = cp0[yo + xB];
                float c1 = cp0[yo + xB + (1 << 16)];
                float d0 = cp0[yo + xB + (8 << 16)];
                float d1 = cp0[yo + xB + (9 << 16)];
                lds[rw * 340 + ldsB]     = pack2(c0, c1);
                lds[rw * 340 + ldsB + 4] = pack2(d0, d1);
            }
        }
    }
    __syncthreads();

    const unsigned char* w1f = ws + ((size_t)(2 * hw) * 9) * 64 * 16; // mtG base = 2*hw
    const unsigned char* w2f = ws + W2F_OFF + (size_t)(4 * hw) * 64 * 16;
    const int cb = TILE_DW + lane * 18;

#pragma unroll 1
    for (int t = 0; t < 8; ++t) {
        const int row = y0 + t;                  // image row of this pair

        // ---- acc1 init = b1 (pre-relu bias) ----
        floatx16 acc1[2];
#pragma unroll
        for (int m = 0; m < 2; ++m) {
            const int hb = 64 * hw + 32 * m + 4 * hi;
#pragma unroll
            for (int rr = 0; rr < 4; ++rr) {
                float4 bv = *(const float4*)(b1 + hb + 8 * rr);
                acc1[m][4 * rr + 0] = bv.x;
                acc1[m][4 * rr + 1] = bv.y;
                acc1[m][4 * rr + 2] = bv.z;
                acc1[m][4 * rr + 3] = bv.w;
            }
        }

        // ---- GEMM1: 9 taps (K=16 each), A = W1eff frags, B = bf16 pixel tile ----
#pragma unroll
        for (int tap = 0; tap < 9; ++tap) {
            const int tr  = t + tap / 3;                // tile row (dy+1 folded in)
            const int col = p + tap % 3;                // tile col (dx+1 folded in)
            const int dwo = (tr * 34 + col) * 10 + 4 * hi;
            union { unsigned int u[4]; short8 s; } bfr;
            uint2 lo2 = *(const uint2*)&lds[dwo];
            uint2 hi2 = *(const uint2*)&lds[dwo + 2];
            bfr.u[0] = lo2.x; bfr.u[1] = lo2.y; bfr.u[2] = hi2.x; bfr.u[3] = hi2.y;
#pragma unroll
            for (int m = 0; m < 2; ++m) {
                short8 af = *(const short8*)(w1f + (size_t)((m * 9 + tap) * 64 + lane) * 16);
                acc1[m] = __builtin_amdgcn_mfma_f32_32x32x16_bf16(af, bfr.s, acc1[m], 0, 0, 0);
            }
        }

        // ---- relu + pack h into 8 runs of 4 bf16 (uint2 each) ----
        uint2 hrun[8];
#pragma unroll
        for (int m = 0; m < 2; ++m)
#pragma unroll
            for (int rr = 0; rr < 4; ++rr) {
                float h0 = fmaxf(acc1[m][4 * rr + 0], 0.f);
                float h1 = fmaxf(acc1[m][4 * rr + 1], 0.f);
                float h2 = fmaxf(acc1[m][4 * rr + 2], 0.f);
                float h3 = fmaxf(acc1[m][4 * rr + 3], 0.f);
                hrun[4 * m + rr].x = pack2(h0, h1);
                hrun[4 * m + rr].y = pack2(h2, h3);
            }

        // ---- GEMM2 (partial over this wave's 64 hids): D[outc32][pixel32] ----
        floatx16 acc2 = {};
#pragma unroll
        for (int sp = 0; sp < 4; ++sp) {
            uint2 r0 = hrun[2 * sp];
            uint2 r1 = hrun[2 * sp + 1];
            uint2 x0s, x1s;
            x0s.x = (unsigned int)__shfl_xor((int)r0.x, 32);
            x0s.y = (unsigned int)__shfl_xor((int)r0.y, 32);
            x1s.x = (unsigned int)__shfl_xor((int)r1.x, 32);
            x1s.y = (unsigned int)__shfl_xor((int)r1.y, 32);
            union { unsigned int u[4]; short8 s; } b2;
            uint2 lo = hi ? x1s : r0;     // k = 16s+8hi+{0..3} from hi=0 half
            uint2 hg = hi ? r1  : x0s;    // k = 16s+8hi+{4..7} from hi=1 half
            b2.u[0] = lo.x; b2.u[1] = lo.y; b2.u[2] = hg.x; b2.u[3] = hg.y;
            short8 a2 = *(const short8*)(w2f + (size_t)(sp * 64 + lane) * 16);
            acc2 = __builtin_amdgcn_mfma_f32_32x32x16_bf16(a2, b2.s, acc2, 0, 0, 0);
        }

        // ---- pair combine: wave1 -> LDS ----
        if (hw == 1) {
#pragma unroll
            for (int k = 0; k < 8; ++k) {
                uint2 v;
                v.x = __float_as_uint(acc2[2 * k]);
                v.y = __float_as_uint(acc2[2 * k + 1]);
                *(uint2*)&lds[cb + 2 * k] = v;
            }
        }
        __syncthreads();

        if (hw == 0) {
            // full ds = own partial + partner partial; residual add; store ch 3..15
#pragma unroll
            for (int r = 0; r < 16; ++r) {
                int outc = (r & 3) + 8 * (r >> 2) + 4 * hi;
                if (outc < OUTC) {
                    float sum = acc2[r] + __uint_as_float(lds[cb + r]);
                    int idx = ((bI * 16 + 3 + outc) << 16) + (row << 8) + x0 + p;
                    out[idx] = in[idx] + sum;
                }
            }
        } else {
            // passthrough channels 0..2 for this row
#pragma unroll
            for (int k = 0; k < 2; ++k) {
                int e = lane + 64 * k;
                if (e < 96) {
                    int c  = e >> 5;
                    int px = e & 31;
                    int idx = ((bI * 16 + c) << 16) + (row << 8) + x0 + px;
                    out[idx] = in[idx];
                }
            }
        }
        __syncthreads();   // protect cbuf reuse next iteration
    }
}

extern "C" void kernel_launch(void* const* d_in, const int* in_sizes, int n_in,
                              void* d_out, int out_size, void* d_ws, size_t ws_size,
                              hipStream_t stream) {
    const float* x  = (const float*)d_in[0];
    const float* w1 = (const float*)d_in[1];
    const float* b1 = (const float*)d_in[2];
    const float* w2 = (const float*)d_in[3];
    float* out = (float*)d_out;
    unsigned char* ws = (unsigned char*)d_ws;

    hipLaunchKernelGGL(gca_prep, dim3(11), dim3(256), 0, stream, w1, w2, ws);
    hipLaunchKernelGGL(gca_main, dim3(4096), dim3(128), 0, stream, x, b1, ws, out);
}